// Round 24
// baseline (687.908 us; speedup 1.0000x reference)
//
#include <hip/hip_runtime.h>
#include <hip/hip_cooperative_groups.h>

namespace cg = cooperative_groups;

// ---------------------------------------------------------------------------
// 2-layer TransformerConv factored through the 2-dim feature spaces.
// Round 24 (= round 22 resubmit; rounds 22/23 both died in pre-push infra
// flake): the 123us plateau persists across every multi-dispatch variant
// with all per-kernel counters <5% busy -> hypothesis: per-dispatch fixed
// cost (drain+launch+cold L2). Decisive test: ONE cooperative kernel, all
// 5 stages separated by grid.sync(). Fallback to the 5-dispatch pipeline
// if cooperative launch is rejected.
// ---------------------------------------------------------------------------

#define R_LOG2 7
#define R_DSTS 128
#define NBPAD  1024            // padded bucket count (N <= 131072)
#define BE     4096            // edges per scatter chunk
#define CAPB   2432            // slots/bucket (mean 2048, 8.5 sigma), %4==0
#define RSQRT2 0.70710678118654752f
#define GRID   768
#define UTPB   256

struct ScS {
    int hist[NBPAD]; int lofs[NBPAD]; int gbase[NBPAD]; int wsum[16];
    int stage[BE]; unsigned short sbkt[BE];
};
struct AgS {
    float cpart[4][9]; float c9[9];
    float p0[R_DSTS], p1[R_DSTS], pc[R_DSTS], ac[3 * R_DSTS];
};
struct PjS { float sW[14][256]; };
union SharedU { ScS sc; AgS ag; PjS pj; };

struct Params {
    const float* x; const int* src; const int* dst;
    const float* Wq1; const float* bq1; const float* Wk1; const float* bk1;
    const float* Wv1; const float* bv1; const float* Ws1; const float* bs1;
    const float* Wq2; const float* bq2; const float* Wk2; const float* bk2;
    const float* Wv2; const float* bv2; const float* Ws2; const float* bs2;
    int* cnt; int* recs; float4* agg1; float4* kv2; float* q2; float* hs2;
    float* out; int N; int E; int NB; int NBlk;
};

// ---- stage bodies (shared by uber kernel and fallback kernels) ------------

template <int T>
__device__ __forceinline__ void scatter_body(
        SharedU* su, int blk, const int* __restrict__ src,
        const int* __restrict__ dst, int* __restrict__ cnt,
        int* __restrict__ recs, int NB, int E) {
    int t = threadIdx.x;
    for (int i = t; i < NBPAD; i += T) su->sc.hist[i] = 0;
    __syncthreads();

    int base = blk * BE;
    int nloc = E - base; if (nloc > BE) nloc = BE;
    int nv = nloc >> 2;
    const int4* d4 = (const int4*)(dst + base);
    const int4* s4 = (const int4*)(src + base);

    for (int i = t; i < nv; i += T) {
        int4 v = d4[i];
        atomicAdd(&su->sc.hist[v.x >> R_LOG2], 1);
        atomicAdd(&su->sc.hist[v.y >> R_LOG2], 1);
        atomicAdd(&su->sc.hist[v.z >> R_LOG2], 1);
        atomicAdd(&su->sc.hist[v.w >> R_LOG2], 1);
    }
    for (int i = (nv << 2) + t; i < nloc; i += T)
        atomicAdd(&su->sc.hist[dst[base + i] >> R_LOG2], 1);
    __syncthreads();

    {   // exclusive scan over NBPAD entries, K = NBPAD/T per thread
        const int K = NBPAD / T;
        int b0 = t * K;
        int h[K];
        int tot = 0;
#pragma unroll
        for (int k = 0; k < K; ++k) { h[k] = su->sc.hist[b0 + k]; tot += h[k]; }
        int lane = t & 63, w = t >> 6;
        int incl = tot;
#pragma unroll
        for (int o = 1; o < 64; o <<= 1) {
            int u = __shfl_up(incl, o);
            if (lane >= o) incl += u;
        }
        if (lane == 63) su->sc.wsum[w] = incl;
        __syncthreads();
        int ex = incl - tot;
        for (int j = 0; j < w; ++j) ex += su->sc.wsum[j];
#pragma unroll
        for (int k = 0; k < K; ++k) { su->sc.lofs[b0 + k] = ex; ex += h[k]; }
    }
    __syncthreads();

    for (int b = t; b < NB; b += T) {
        int h = su->sc.hist[b];
        int start = h ? atomicAdd(&cnt[b], h) : 0;
        su->sc.gbase[b] = b * CAPB + start - su->sc.lofs[b];
        su->sc.hist[b] = 0;
    }
    __syncthreads();

    for (int i = t; i < nv; i += T) {
        int4 dv = d4[i]; int4 sv = s4[i]; int d, b, r, p;
        d = dv.x; b = d >> R_LOG2; r = atomicAdd(&su->sc.hist[b], 1); p = su->sc.lofs[b] + r;
        su->sc.stage[p] = sv.x | ((d & (R_DSTS - 1)) << 17); su->sc.sbkt[p] = (unsigned short)b;
        d = dv.y; b = d >> R_LOG2; r = atomicAdd(&su->sc.hist[b], 1); p = su->sc.lofs[b] + r;
        su->sc.stage[p] = sv.y | ((d & (R_DSTS - 1)) << 17); su->sc.sbkt[p] = (unsigned short)b;
        d = dv.z; b = d >> R_LOG2; r = atomicAdd(&su->sc.hist[b], 1); p = su->sc.lofs[b] + r;
        su->sc.stage[p] = sv.z | ((d & (R_DSTS - 1)) << 17); su->sc.sbkt[p] = (unsigned short)b;
        d = dv.w; b = d >> R_LOG2; r = atomicAdd(&su->sc.hist[b], 1); p = su->sc.lofs[b] + r;
        su->sc.stage[p] = sv.w | ((d & (R_DSTS - 1)) << 17); su->sc.sbkt[p] = (unsigned short)b;
    }
    for (int i = (nv << 2) + t; i < nloc; i += T) {
        int d = dst[base + i];
        int b = d >> R_LOG2;
        int r = atomicAdd(&su->sc.hist[b], 1);
        int p = su->sc.lofs[b] + r;
        su->sc.stage[p] = src[base + i] | ((d & (R_DSTS - 1)) << 17);
        su->sc.sbkt[p] = (unsigned short)b;
    }
    __syncthreads();

    for (int i = t; i < nloc; i += T) {
        int bk = su->sc.sbkt[i];
        int p = su->sc.gbase[bk] + i;
        if (p < (bk + 1) * CAPB) recs[p] = su->sc.stage[i];
    }
    __syncthreads();
}

template <int T>
__device__ __forceinline__ void coeff_body(
        SharedU* su, const float* __restrict__ Wq1, const float* __restrict__ bq1,
        const float* __restrict__ Wk1, const float* __restrict__ bk1) {
    int t = threadIdx.x;
    if (t < 256) {
        float wq0 = Wq1[t], wq1 = Wq1[256 + t];
        float wk0 = Wk1[t], wk1 = Wk1[256 + t];
        float bq = bq1[t], bk = bk1[t];
        float vals[9] = { wq0 * wk0, wq0 * wk1, wq1 * wk0, wq1 * wk1,
                          wq0 * bk,  wq1 * bk,  bq * wk0,  bq * wk1,  bq * bk };
        int lane = t & 63, w = t >> 6;
#pragma unroll
        for (int i = 0; i < 9; ++i) {
            float v = vals[i];
#pragma unroll
            for (int o = 32; o > 0; o >>= 1) v += __shfl_xor(v, o);
            if (lane == 0) su->ag.cpart[w][i] = v;
        }
    }
    __syncthreads();
    if (t < 9)
        su->ag.c9[t] = su->ag.cpart[0][t] + su->ag.cpart[1][t]
                     + su->ag.cpart[2][t] + su->ag.cpart[3][t];
    __syncthreads();
}

template <int T>
__device__ __forceinline__ void l1bucket_body(
        SharedU* su, int b, const float* __restrict__ x,
        const int* __restrict__ recs, const int* __restrict__ cnt,
        float4* __restrict__ agg1, int N) {
    int t = threadIdx.x;
    int nbase = b << R_LOG2;
    int rem = N - nbase; if (rem > R_DSTS) rem = R_DSTS;
    for (int i = t; i < 3 * R_DSTS; i += T) su->ag.ac[i] = 0.f;
    if (t < rem) {
        float2 xd = ((const float2*)x)[nbase + t];
        su->ag.p0[t] = su->ag.c9[0] * xd.x + su->ag.c9[2] * xd.y + su->ag.c9[6];
        su->ag.p1[t] = su->ag.c9[1] * xd.x + su->ag.c9[3] * xd.y + su->ag.c9[7];
        su->ag.pc[t] = su->ag.c9[4] * xd.x + su->ag.c9[5] * xd.y + su->ag.c9[8];
    }
    __syncthreads();

    const float2* x2 = (const float2*)x;
    int cb = cnt[b]; if (cb > CAPB) cb = CAPB;
    const int* rb = recs + (size_t)b * CAPB;
    const int4* rb4 = (const int4*)rb;
    int nv4 = cb >> 2;
    for (int i = t; i < nv4; i += T) {
        int4 r = rb4[i];
        int s0 = r.x & 0x1FFFF, d0 = (r.x >> 17) & (R_DSTS - 1);
        int s1 = r.y & 0x1FFFF, d1 = (r.y >> 17) & (R_DSTS - 1);
        int s2 = r.z & 0x1FFFF, d2 = (r.z >> 17) & (R_DSTS - 1);
        int s3 = r.w & 0x1FFFF, d3 = (r.w >> 17) & (R_DSTS - 1);
        float2 xa = x2[s0], xb = x2[s1], xc = x2[s2], xd = x2[s3];
        float w0 = __expf((su->ag.p0[d0] * xa.x + su->ag.p1[d0] * xa.y + su->ag.pc[d0]) * 0.0625f);
        float w1 = __expf((su->ag.p0[d1] * xb.x + su->ag.p1[d1] * xb.y + su->ag.pc[d1]) * 0.0625f);
        float w2 = __expf((su->ag.p0[d2] * xc.x + su->ag.p1[d2] * xc.y + su->ag.pc[d2]) * 0.0625f);
        float w3 = __expf((su->ag.p0[d3] * xd.x + su->ag.p1[d3] * xd.y + su->ag.pc[d3]) * 0.0625f);
        atomicAdd(&su->ag.ac[d0], w0); atomicAdd(&su->ag.ac[R_DSTS + d0], w0 * xa.x); atomicAdd(&su->ag.ac[2 * R_DSTS + d0], w0 * xa.y);
        atomicAdd(&su->ag.ac[d1], w1); atomicAdd(&su->ag.ac[R_DSTS + d1], w1 * xb.x); atomicAdd(&su->ag.ac[2 * R_DSTS + d1], w1 * xb.y);
        atomicAdd(&su->ag.ac[d2], w2); atomicAdd(&su->ag.ac[R_DSTS + d2], w2 * xc.x); atomicAdd(&su->ag.ac[2 * R_DSTS + d2], w2 * xc.y);
        atomicAdd(&su->ag.ac[d3], w3); atomicAdd(&su->ag.ac[R_DSTS + d3], w3 * xd.x); atomicAdd(&su->ag.ac[2 * R_DSTS + d3], w3 * xd.y);
    }
    for (int i = (nv4 << 2) + t; i < cb; i += T) {
        int rec = rb[i];
        int s = rec & 0x1FFFF, dl = (rec >> 17) & (R_DSTS - 1);
        float2 xs = x2[s];
        float w = __expf((su->ag.p0[dl] * xs.x + su->ag.p1[dl] * xs.y + su->ag.pc[dl]) * 0.0625f);
        atomicAdd(&su->ag.ac[dl], w);
        atomicAdd(&su->ag.ac[R_DSTS + dl], w * xs.x);
        atomicAdd(&su->ag.ac[2 * R_DSTS + dl], w * xs.y);
    }
    __syncthreads();
    if (t < rem)
        agg1[nbase + t] = make_float4(su->ag.ac[t], su->ag.ac[R_DSTS + t],
                                      su->ag.ac[2 * R_DSTS + t], 0.f);
    __syncthreads();
}

template <int T>
__device__ __forceinline__ void proj_chunk_body(
        SharedU* su, int nb0, const float* __restrict__ x,
        const float4* __restrict__ agg1,
        const float* __restrict__ bq2, const float* __restrict__ bk2,
        const float* __restrict__ bv2, const float* __restrict__ bs2,
        float* __restrict__ q2, float4* __restrict__ kv2,
        float* __restrict__ hs2, int N) {
    int t = threadIdx.x;
    int g = t & 7, grp = t >> 3;
    int nb = nb0 + grp * 4;

    float a0[4], a1[4], he[4], xdx[4], xdy[4];
#pragma unroll
    for (int k = 0; k < 4; ++k) {
        int n = nb + k;
        a0[k] = 0.f; a1[k] = 0.f; he[k] = 0.f; xdx[k] = 0.f; xdy[k] = 0.f;
        if (n < N) {
            float4 ag = agg1[n];
            if (ag.x > 0.f) {
                float inv = 1.0f / ag.x;
                a0[k] = ag.y * inv; a1[k] = ag.z * inv; he[k] = 1.f;
            }
            float2 xd = ((const float2*)x)[n];
            xdx[k] = xd.x; xdy[k] = xd.y;
        }
    }
    float acc[4][8];
#pragma unroll
    for (int k = 0; k < 4; ++k)
#pragma unroll
        for (int i = 0; i < 8; ++i) acc[k][i] = 0.f;

#pragma unroll 1
    for (int j = 0; j < 8; ++j) {
        int ci = g + 8 * j;
        float4 hk[4];
        {
            float4 w0 = ((const float4*)su->pj.sW[0])[ci];
            float4 w1 = ((const float4*)su->pj.sW[1])[ci];
            float4 w2 = ((const float4*)su->pj.sW[2])[ci];
            float4 w3 = ((const float4*)su->pj.sW[3])[ci];
            float4 w4 = ((const float4*)su->pj.sW[4])[ci];
            float4 w5 = ((const float4*)su->pj.sW[5])[ci];
#pragma unroll
            for (int k = 0; k < 4; ++k) {
                hk[k].x = fmaxf(a0[k]*w0.x + a1[k]*w1.x + xdx[k]*w2.x + xdy[k]*w3.x + he[k]*w4.x + w5.x, 0.f);
                hk[k].y = fmaxf(a0[k]*w0.y + a1[k]*w1.y + xdx[k]*w2.y + xdy[k]*w3.y + he[k]*w4.y + w5.y, 0.f);
                hk[k].z = fmaxf(a0[k]*w0.z + a1[k]*w1.z + xdx[k]*w2.z + xdy[k]*w3.z + he[k]*w4.z + w5.z, 0.f);
                hk[k].w = fmaxf(a0[k]*w0.w + a1[k]*w1.w + xdx[k]*w2.w + xdy[k]*w3.w + he[k]*w4.w + w5.w, 0.f);
            }
        }
#pragma unroll
        for (int i = 0; i < 8; ++i) {
            float4 u = ((const float4*)su->pj.sW[6 + i])[ci];
#pragma unroll
            for (int k = 0; k < 4; ++k)
                acc[k][i] += hk[k].x*u.x + hk[k].y*u.y + hk[k].z*u.z + hk[k].w*u.w;
        }
    }
#pragma unroll
    for (int k = 0; k < 4; ++k)
#pragma unroll
        for (int i = 0; i < 8; ++i) {
#pragma unroll
            for (int m = 1; m < 8; m <<= 1)
                acc[k][i] += __shfl_xor(acc[k][i], m);
        }
    if (g < 4) {
        int n = nb + g;
        if (n < N) {
            ((float2*)q2)[n]  = make_float2(acc[g][0] + bq2[0], acc[g][1] + bq2[1]);
            kv2[n] = make_float4(acc[g][2] + bk2[0], acc[g][3] + bk2[1],
                                 acc[g][4] + bv2[0], acc[g][5] + bv2[1]);
            ((float2*)hs2)[n] = make_float2(acc[g][6] + bs2[0], acc[g][7] + bs2[1]);
        }
    }
}

template <int T>
__device__ __forceinline__ void l2bucket_body(
        SharedU* su, int b, const float* __restrict__ q2,
        const float4* __restrict__ kv2, const float* __restrict__ hs2,
        const int* __restrict__ recs, const int* __restrict__ cnt,
        float* __restrict__ out, int N) {
    int t = threadIdx.x;
    int nbase = b << R_LOG2;
    int rem = N - nbase; if (rem > R_DSTS) rem = R_DSTS;
    for (int i = t; i < 3 * R_DSTS; i += T) su->ag.ac[i] = 0.f;
    if (t < rem) {
        float2 q = ((const float2*)q2)[nbase + t];
        su->ag.p0[t] = q.x * RSQRT2;
        su->ag.p1[t] = q.y * RSQRT2;
    }
    __syncthreads();

    int cb = cnt[b]; if (cb > CAPB) cb = CAPB;
    const int* rb = recs + (size_t)b * CAPB;
    const int4* rb4 = (const int4*)rb;
    int nv4 = cb >> 2;
    for (int i = t; i < nv4; i += T) {
        int4 r = rb4[i];
        int s0 = r.x & 0x1FFFF, d0 = (r.x >> 17) & (R_DSTS - 1);
        int s1 = r.y & 0x1FFFF, d1 = (r.y >> 17) & (R_DSTS - 1);
        int s2 = r.z & 0x1FFFF, d2 = (r.z >> 17) & (R_DSTS - 1);
        int s3 = r.w & 0x1FFFF, d3 = (r.w >> 17) & (R_DSTS - 1);
        float4 ka = kv2[s0], kb = kv2[s1], kc = kv2[s2], kd = kv2[s3];
        float w0 = __expf(su->ag.p0[d0] * ka.x + su->ag.p1[d0] * ka.y);
        float w1 = __expf(su->ag.p0[d1] * kb.x + su->ag.p1[d1] * kb.y);
        float w2 = __expf(su->ag.p0[d2] * kc.x + su->ag.p1[d2] * kc.y);
        float w3 = __expf(su->ag.p0[d3] * kd.x + su->ag.p1[d3] * kd.y);
        atomicAdd(&su->ag.ac[d0], w0); atomicAdd(&su->ag.ac[R_DSTS + d0], w0 * ka.z); atomicAdd(&su->ag.ac[2 * R_DSTS + d0], w0 * ka.w);
        atomicAdd(&su->ag.ac[d1], w1); atomicAdd(&su->ag.ac[R_DSTS + d1], w1 * kb.z); atomicAdd(&su->ag.ac[2 * R_DSTS + d1], w1 * kb.w);
        atomicAdd(&su->ag.ac[d2], w2); atomicAdd(&su->ag.ac[R_DSTS + d2], w2 * kc.z); atomicAdd(&su->ag.ac[2 * R_DSTS + d2], w2 * kc.w);
        atomicAdd(&su->ag.ac[d3], w3); atomicAdd(&su->ag.ac[R_DSTS + d3], w3 * kd.z); atomicAdd(&su->ag.ac[2 * R_DSTS + d3], w3 * kd.w);
    }
    for (int i = (nv4 << 2) + t; i < cb; i += T) {
        int rec = rb[i];
        int s = rec & 0x1FFFF, dl = (rec >> 17) & (R_DSTS - 1);
        float4 kv = kv2[s];
        float w = __expf(su->ag.p0[dl] * kv.x + su->ag.p1[dl] * kv.y);
        atomicAdd(&su->ag.ac[dl], w);
        atomicAdd(&su->ag.ac[R_DSTS + dl], w * kv.z);
        atomicAdd(&su->ag.ac[2 * R_DSTS + dl], w * kv.w);
    }
    __syncthreads();

    if (t < rem) {
        int n = nbase + t;
        float s = su->ag.ac[t];
        float g0 = 0.f, g1 = 0.f;
        if (s > 0.f) {
            float inv = 1.0f / s;
            g0 = su->ag.ac[R_DSTS + t] * inv; g1 = su->ag.ac[2 * R_DSTS + t] * inv;
        }
        float2 hs = ((const float2*)hs2)[n];
        float o0 = g0 + hs.x;
        float o1 = g1 + hs.y;
        float mx = fmaxf(o0, o1), mn = fminf(o0, o1);
        float lse = mx + log1pf(__expf(mn - mx));
        ((float2*)out)[n] = make_float2(o0 - lse, o1 - lse);
    }
    __syncthreads();
}

__device__ __forceinline__ void load_proj_weights(SharedU* su, const Params& P) {
    int t = threadIdx.x;
    su->pj.sW[0][t]  = P.Wv1[t];
    su->pj.sW[1][t]  = P.Wv1[256 + t];
    su->pj.sW[2][t]  = P.Ws1[t];
    su->pj.sW[3][t]  = P.Ws1[256 + t];
    su->pj.sW[4][t]  = P.bv1[t];
    su->pj.sW[5][t]  = P.bs1[t];
    su->pj.sW[6][t]  = P.Wq2[2 * t];
    su->pj.sW[7][t]  = P.Wq2[2 * t + 1];
    su->pj.sW[8][t]  = P.Wk2[2 * t];
    su->pj.sW[9][t]  = P.Wk2[2 * t + 1];
    su->pj.sW[10][t] = P.Wv2[2 * t];
    su->pj.sW[11][t] = P.Wv2[2 * t + 1];
    su->pj.sW[12][t] = P.Ws2[2 * t];
    su->pj.sW[13][t] = P.Ws2[2 * t + 1];
    __syncthreads();
}

// ---- the single cooperative kernel ----------------------------------------

__global__ __launch_bounds__(UTPB, 4) void uber_k(Params P) {
    cg::grid_group gg = cg::this_grid();
    __shared__ SharedU su;
    int t = threadIdx.x, bid = blockIdx.x;

    // Stage A: zero cnt
    int gtid = bid * UTPB + t;
    if (gtid < P.NB) P.cnt[gtid] = 0;
    __threadfence();
    gg.sync();

    // Stage B: scatter
    if (bid < P.NBlk)
        scatter_body<UTPB>(&su, bid, P.src, P.dst, P.cnt, P.recs, P.NB, P.E);
    __threadfence();
    gg.sync();

    // Stage C: layer-1 bucket reduce (grid-stride)
    coeff_body<UTPB>(&su, P.Wq1, P.bq1, P.Wk1, P.bk1);
    for (int b = bid; b < P.NB; b += GRID)
        l1bucket_body<UTPB>(&su, b, P.x, P.recs, P.cnt, P.agg1, P.N);
    __threadfence();
    gg.sync();

    // Stage D: node projection (grid-stride over 128-node chunks)
    load_proj_weights(&su, P);
    for (int c = bid; c * 128 < P.N; c += GRID)
        proj_chunk_body<UTPB>(&su, c * 128, P.x, P.agg1, P.bq2, P.bk2,
                              P.bv2, P.bs2, P.q2, P.kv2, P.hs2, P.N);
    __threadfence();
    gg.sync();

    // Stage E: layer-2 bucket reduce + skip + log_softmax
    for (int b = bid; b < P.NB; b += GRID)
        l2bucket_body<UTPB>(&su, b, P.q2, P.kv2, P.hs2, P.recs, P.cnt,
                            P.out, P.N);
}

// ---- fallback (non-cooperative) kernels -----------------------------------

__global__ __launch_bounds__(1024) void scatter1f_k(
        const int* src, const int* dst, int* cnt, int* recs, int NB, int E) {
    __shared__ SharedU su;
    scatter_body<1024>(&su, blockIdx.x, src, dst, cnt, recs, NB, E);
}

__global__ __launch_bounds__(512) void l1aggf_k(
        const float* x, const float* Wq1, const float* bq1,
        const float* Wk1, const float* bk1,
        const int* recs, const int* cnt, float4* agg1, int N) {
    __shared__ SharedU su;
    coeff_body<512>(&su, Wq1, bq1, Wk1, bk1);
    l1bucket_body<512>(&su, blockIdx.x, x, recs, cnt, agg1, N);
}

__global__ __launch_bounds__(256, 4) void projf_k(Params P) {
    __shared__ SharedU su;
    load_proj_weights(&su, P);
    proj_chunk_body<256>(&su, blockIdx.x * 128, P.x, P.agg1, P.bq2, P.bk2,
                         P.bv2, P.bs2, P.q2, P.kv2, P.hs2, P.N);
}

__global__ __launch_bounds__(512) void l2outf_k(
        const float* q2, const float4* kv2, const float* hs2,
        const int* recs, const int* cnt, float* out, int N) {
    __shared__ SharedU su;
    l2bucket_body<512>(&su, blockIdx.x, q2, kv2, hs2, recs, cnt, out, N);
}

// ---------------------------------------------------------------------------

extern "C" void kernel_launch(void* const* d_in, const int* in_sizes, int n_in,
                              void* d_out, int out_size, void* d_ws, size_t ws_size,
                              hipStream_t stream) {
    const float* x   = (const float*)d_in[0];
    const int*   ei  = (const int*)d_in[1];

    const int N = in_sizes[0] / 2;
    const int E = in_sizes[1] / 2;

    const int NB   = (N + R_DSTS - 1) >> R_LOG2;   // 782
    const int NBlk = (E + BE - 1) / BE;            // 391

    float* ws = (float*)d_ws;
    size_t off = 0;
    int*   cnt  = (int*)(ws + off);      off += NBPAD;
    int*   recs = (int*)(ws + off);      off += (size_t)NB * CAPB;
    off = (off + 3) & ~(size_t)3;
    float4* agg1 = (float4*)(ws + off);  off += 4 * (size_t)N;
    float4* kv2  = (float4*)(ws + off);  off += 4 * (size_t)N;
    float* q2    = ws + off;             off += 2 * (size_t)N;
    float* hs2   = ws + off;             off += 2 * (size_t)N;

    Params P;
    P.x = x; P.src = ei; P.dst = ei + E;
    P.Wq1 = (const float*)d_in[2];  P.bq1 = (const float*)d_in[3];
    P.Wk1 = (const float*)d_in[4];  P.bk1 = (const float*)d_in[5];
    P.Wv1 = (const float*)d_in[6];  P.bv1 = (const float*)d_in[7];
    P.Ws1 = (const float*)d_in[8];  P.bs1 = (const float*)d_in[9];
    P.Wq2 = (const float*)d_in[10]; P.bq2 = (const float*)d_in[11];
    P.Wk2 = (const float*)d_in[12]; P.bk2 = (const float*)d_in[13];
    P.Wv2 = (const float*)d_in[14]; P.bv2 = (const float*)d_in[15];
    P.Ws2 = (const float*)d_in[16]; P.bs2 = (const float*)d_in[17];
    P.cnt = cnt; P.recs = recs; P.agg1 = agg1; P.kv2 = kv2;
    P.q2 = q2; P.hs2 = hs2; P.out = (float*)d_out;
    P.N = N; P.E = E; P.NB = NB; P.NBlk = NBlk;

    void* args[] = { (void*)&P };
    hipError_t err = hipLaunchCooperativeKernel((const void*)uber_k,
                                                dim3(GRID), dim3(UTPB),
                                                args, 0, stream);
    if (err != hipSuccess) {
        // fallback: 5-dispatch pipeline (round-21 structure, same bodies)
        hipMemsetAsync(cnt, 0, NBPAD * sizeof(int), stream);
        scatter1f_k<<<NBlk, 1024, 0, stream>>>(P.src, P.dst, cnt, recs, NB, E);
        l1aggf_k<<<NB, 512, 0, stream>>>(x, P.Wq1, P.bq1, P.Wk1, P.bk1,
                                         recs, cnt, agg1, N);
        projf_k<<<(N + 127) / 128, 256, 0, stream>>>(P);
        l2outf_k<<<NB, 512, 0, stream>>>(q2, kv2, hs2, recs, cnt,
                                         (float*)d_out, N);
    }
}

// Round 25
// 120.565 us; speedup vs baseline: 5.7057x; 5.7057x over previous
//
#include <hip/hip_runtime.h>

// ---------------------------------------------------------------------------
// 2-layer TransformerConv factored through the 2-dim feature spaces.
// Round 25: revert cooperative fusion (round 24: grid.sync cost 693us).
// Evidence from rounds 13-20 profiles: a 3KB memset node costs ~40us ->
// per-NODE fixed overhead dominates the 123us plateau. Cut nodes 5 -> 4:
// proj fused into l1agg's tail (dependency is block-local: bucket b's
// reduce feeds exactly nodes [b*128, b*128+128)), softmax sums consumed
// straight from LDS -- no agg1 round-trip, no proj dispatch.
// Pipeline: memset(cnt) -> scatter1 -> l1proj -> l2out.
// ---------------------------------------------------------------------------

#define R_LOG2   7
#define R_DSTS   128            // dsts per bucket
#define BE       4096           // edges per partition block
#define MAXNB    1024           // supports N <= 131072
#define CAPB     2432           // slots per bucket (mean 2048, 8.5 sigma), %4==0
#define RSQRT2   0.70710678118654752f

// Single-pass locally-sorted scatter, 1024 threads (16 waves) per block.
// LDS histogram -> in-block scan -> global segment reservation (1 atomicAdd
// per touched bucket) -> rank & stage in bucket order -> ordered coalesced
// segment writes. (Verified rounds 14-21.)
__global__ __launch_bounds__(1024) void scatter1_k(
        const int* __restrict__ src, const int* __restrict__ dst,
        int* __restrict__ cnt, int* __restrict__ recs, int NB, int E) {
    __shared__ int hist[MAXNB];
    __shared__ int lofs[MAXNB];
    __shared__ int gbase[MAXNB];
    __shared__ int stage[BE];
    __shared__ unsigned short sbkt[BE];
    __shared__ int wsum[16];
    int t = threadIdx.x;
    if (t < NB) hist[t] = 0;
    __syncthreads();

    int base = blockIdx.x * BE;
    int nloc = E - base; if (nloc > BE) nloc = BE;
    int nv = nloc >> 2;
    const int4* d4 = (const int4*)(dst + base);
    const int4* s4 = (const int4*)(src + base);

    // pass 1: local histogram (4 edges/thread via int4)
    for (int i = t; i < nv; i += 1024) {
        int4 v = d4[i];
        atomicAdd(&hist[v.x >> R_LOG2], 1);
        atomicAdd(&hist[v.y >> R_LOG2], 1);
        atomicAdd(&hist[v.z >> R_LOG2], 1);
        atomicAdd(&hist[v.w >> R_LOG2], 1);
    }
    for (int i = (nv << 2) + t; i < nloc; i += 1024)
        atomicAdd(&hist[dst[base + i] >> R_LOG2], 1);
    __syncthreads();

    // in-block exclusive scan hist -> lofs (1 entry/thread, NB<=1024)
    {
        int v = (t < NB) ? hist[t] : 0;
        int lane = t & 63, w = t >> 6;   // 16 waves
        int incl = v;
#pragma unroll
        for (int o = 1; o < 64; o <<= 1) {
            int u = __shfl_up(incl, o);
            if (lane >= o) incl += u;
        }
        if (lane == 63) wsum[w] = incl;
        __syncthreads();
        int ex = incl - v;
        for (int j = 0; j < w; ++j) ex += wsum[j];
        if (t < NB) lofs[t] = ex;
    }
    __syncthreads();

    // reserve a contiguous segment in each touched bucket, reset hist
    if (t < NB) {
        int h = hist[t];
        int start = h ? atomicAdd(&cnt[t], h) : 0;
        gbase[t] = t * CAPB + start - lofs[t];
        hist[t] = 0;
    }
    __syncthreads();

    // pass 2: rank & stage in bucket-sorted order
    for (int i = t; i < nv; i += 1024) {
        int4 dv = d4[i];
        int4 sv = s4[i];
        int d, b, r, p;
        d = dv.x; b = d >> R_LOG2; r = atomicAdd(&hist[b], 1); p = lofs[b] + r;
        stage[p] = sv.x | ((d & (R_DSTS - 1)) << 17); sbkt[p] = (unsigned short)b;
        d = dv.y; b = d >> R_LOG2; r = atomicAdd(&hist[b], 1); p = lofs[b] + r;
        stage[p] = sv.y | ((d & (R_DSTS - 1)) << 17); sbkt[p] = (unsigned short)b;
        d = dv.z; b = d >> R_LOG2; r = atomicAdd(&hist[b], 1); p = lofs[b] + r;
        stage[p] = sv.z | ((d & (R_DSTS - 1)) << 17); sbkt[p] = (unsigned short)b;
        d = dv.w; b = d >> R_LOG2; r = atomicAdd(&hist[b], 1); p = lofs[b] + r;
        stage[p] = sv.w | ((d & (R_DSTS - 1)) << 17); sbkt[p] = (unsigned short)b;
    }
    for (int i = (nv << 2) + t; i < nloc; i += 1024) {
        int d = dst[base + i];
        int b = d >> R_LOG2;
        int r = atomicAdd(&hist[b], 1);
        int p = lofs[b] + r;
        stage[p] = src[base + i] | ((d & (R_DSTS - 1)) << 17);
        sbkt[p] = (unsigned short)b;
    }
    __syncthreads();

    // pass 3: ordered write — consecutive i -> consecutive addresses per
    // segment; bound-checked against the bucket's fixed capacity.
    for (int i = t; i < nloc; i += 1024) {
        int bk = sbkt[i];
        int p = gbase[bk] + i;
        if (p < (bk + 1) * CAPB) recs[p] = stage[i];
    }
}

// Layer-1 bucket reduce FUSED with the node projection for the bucket's own
// 128 nodes. One bucket per block, 512 threads. Softmax sums consumed
// straight from LDS (no agg1 global array).
__global__ __launch_bounds__(512) void l1proj_k(
        const float* __restrict__ x,
        const float* __restrict__ Wq1, const float* __restrict__ bq1,
        const float* __restrict__ Wk1, const float* __restrict__ bk1,
        const float* __restrict__ Wv1, const float* __restrict__ bv1,
        const float* __restrict__ Ws1, const float* __restrict__ bs1,
        const float* __restrict__ Wq2, const float* __restrict__ bq2,
        const float* __restrict__ Wk2, const float* __restrict__ bk2,
        const float* __restrict__ Wv2, const float* __restrict__ bv2,
        const float* __restrict__ Ws2, const float* __restrict__ bs2,
        const int* __restrict__ recs, const int* __restrict__ cnt,
        float* __restrict__ q2, float4* __restrict__ kv2,
        float* __restrict__ hs2, int N) {
    __shared__ float cpart[4][9];
    __shared__ float c9[9];
    __shared__ float p0[R_DSTS], p1[R_DSTS], pc[R_DSTS];
    __shared__ float ac[3 * R_DSTS];
    __shared__ float sW[14][256];
    int t = threadIdx.x;

    // inline coeff reduction (alpha = xd^T M xs + u.xd + w.xs + c)
    if (t < 256) {
        float wq0 = Wq1[t], wq1 = Wq1[256 + t];
        float wk0 = Wk1[t], wk1 = Wk1[256 + t];
        float bq = bq1[t], bk = bk1[t];
        float vals[9] = { wq0 * wk0, wq0 * wk1, wq1 * wk0, wq1 * wk1,
                          wq0 * bk,  wq1 * bk,  bq * wk0,  bq * wk1,  bq * bk };
        int lane = t & 63, w = t >> 6;
#pragma unroll
        for (int i = 0; i < 9; ++i) {
            float v = vals[i];
#pragma unroll
            for (int o = 32; o > 0; o >>= 1) v += __shfl_xor(v, o);
            if (lane == 0) cpart[w][i] = v;
        }
    } else if (t < 512) {
        // co-load projection weights while waves 0-3 do the coeff butterfly
        int c = t - 256;
        sW[0][c]  = Wv1[c];
        sW[1][c]  = Wv1[256 + c];
        sW[2][c]  = Ws1[c];
        sW[3][c]  = Ws1[256 + c];
        sW[4][c]  = bv1[c];
        sW[5][c]  = bs1[c];
        sW[6][c]  = Wq2[2 * c];
        sW[7][c]  = Wq2[2 * c + 1];
        sW[8][c]  = Wk2[2 * c];
        sW[9][c]  = Wk2[2 * c + 1];
        sW[10][c] = Wv2[2 * c];
        sW[11][c] = Wv2[2 * c + 1];
        sW[12][c] = Ws2[2 * c];
        sW[13][c] = Ws2[2 * c + 1];
    }
    __syncthreads();
    if (t < 256) {
        // second half of the weight rows (cols 0..255 done above by 256..511)
        // nothing: full rows already loaded (256 cols each). finish coeff:
    }
    if (t < 9) c9[t] = cpart[0][t] + cpart[1][t] + cpart[2][t] + cpart[3][t];
    __syncthreads();

    int b = blockIdx.x;
    int nbase = b << R_LOG2;
    int rem = N - nbase; if (rem > R_DSTS) rem = R_DSTS;

    if (t < 3 * R_DSTS) ac[t] = 0.f;
    if (t < rem) {
        float2 xd = ((const float2*)x)[nbase + t];
        p0[t] = c9[0] * xd.x + c9[2] * xd.y + c9[6];
        p1[t] = c9[1] * xd.x + c9[3] * xd.y + c9[7];
        pc[t] = c9[4] * xd.x + c9[5] * xd.y + c9[8];
    }
    __syncthreads();

    // ---- bucket edge reduce (int4 rec loads, 4 concurrent gathers) ----
    const float2* x2 = (const float2*)x;
    int cb = cnt[b]; if (cb > CAPB) cb = CAPB;
    const int* rb = recs + (size_t)b * CAPB;
    const int4* rb4 = (const int4*)rb;
    int nv4 = cb >> 2;
    for (int i = t; i < nv4; i += 512) {
        int4 r = rb4[i];
        int s0 = r.x & 0x1FFFF, d0 = (r.x >> 17) & (R_DSTS - 1);
        int s1 = r.y & 0x1FFFF, d1 = (r.y >> 17) & (R_DSTS - 1);
        int s2 = r.z & 0x1FFFF, d2 = (r.z >> 17) & (R_DSTS - 1);
        int s3 = r.w & 0x1FFFF, d3 = (r.w >> 17) & (R_DSTS - 1);
        float2 xa = x2[s0];
        float2 xb = x2[s1];
        float2 xc = x2[s2];
        float2 xd = x2[s3];
        float w0 = __expf((p0[d0] * xa.x + p1[d0] * xa.y + pc[d0]) * 0.0625f);
        float w1 = __expf((p0[d1] * xb.x + p1[d1] * xb.y + pc[d1]) * 0.0625f);
        float w2 = __expf((p0[d2] * xc.x + p1[d2] * xc.y + pc[d2]) * 0.0625f);
        float w3 = __expf((p0[d3] * xd.x + p1[d3] * xd.y + pc[d3]) * 0.0625f);
        atomicAdd(&ac[d0], w0); atomicAdd(&ac[R_DSTS + d0], w0 * xa.x); atomicAdd(&ac[2 * R_DSTS + d0], w0 * xa.y);
        atomicAdd(&ac[d1], w1); atomicAdd(&ac[R_DSTS + d1], w1 * xb.x); atomicAdd(&ac[2 * R_DSTS + d1], w1 * xb.y);
        atomicAdd(&ac[d2], w2); atomicAdd(&ac[R_DSTS + d2], w2 * xc.x); atomicAdd(&ac[2 * R_DSTS + d2], w2 * xc.y);
        atomicAdd(&ac[d3], w3); atomicAdd(&ac[R_DSTS + d3], w3 * xd.x); atomicAdd(&ac[2 * R_DSTS + d3], w3 * xd.y);
    }
    for (int i = (nv4 << 2) + t; i < cb; i += 512) {
        int rec = rb[i];
        int s = rec & 0x1FFFF;
        int dl = (rec >> 17) & (R_DSTS - 1);
        float2 xs = x2[s];
        float w = __expf((p0[dl] * xs.x + p1[dl] * xs.y + pc[dl]) * 0.0625f);
        atomicAdd(&ac[dl], w);
        atomicAdd(&ac[R_DSTS + dl], w * xs.x);
        atomicAdd(&ac[2 * R_DSTS + dl], w * xs.y);
    }
    __syncthreads();

    // ---- fused projection of this bucket's 128 nodes ----
    // 8-lane group per TWO nodes: 512 threads = 64 groups x 2 = 128 nodes.
    int g = t & 7;
    int grp = t >> 3;                       // 0..63
    int i0 = grp * 2;                       // local node index base

    float a0[2], a1[2], he[2], xdx[2], xdy[2];
#pragma unroll
    for (int k = 0; k < 2; ++k) {
        int idx = i0 + k;
        int n = nbase + idx;
        a0[k] = 0.f; a1[k] = 0.f; he[k] = 0.f; xdx[k] = 0.f; xdy[k] = 0.f;
        if (idx < rem) {
            float s = ac[idx];              // LDS broadcast (full sums)
            if (s > 0.f) {
                float inv = 1.0f / s;
                a0[k] = ac[R_DSTS + idx] * inv;
                a1[k] = ac[2 * R_DSTS + idx] * inv;
                he[k] = 1.f;
            }
            float2 xd = ((const float2*)x)[n];
            xdx[k] = xd.x; xdy[k] = xd.y;
        }
    }

    float acc[2][8];
#pragma unroll
    for (int k = 0; k < 2; ++k)
#pragma unroll
        for (int i = 0; i < 8; ++i) acc[k][i] = 0.f;

#pragma unroll 1
    for (int j = 0; j < 8; ++j) {
        int ci = g + 8 * j;  // float4 index; channels 4*ci..4*ci+3
        float4 hk[2];
        {
            float4 w0 = ((const float4*)sW[0])[ci];
            float4 w1 = ((const float4*)sW[1])[ci];
            float4 w2 = ((const float4*)sW[2])[ci];
            float4 w3 = ((const float4*)sW[3])[ci];
            float4 w4 = ((const float4*)sW[4])[ci];
            float4 w5 = ((const float4*)sW[5])[ci];
#pragma unroll
            for (int k = 0; k < 2; ++k) {
                hk[k].x = fmaxf(a0[k]*w0.x + a1[k]*w1.x + xdx[k]*w2.x + xdy[k]*w3.x + he[k]*w4.x + w5.x, 0.f);
                hk[k].y = fmaxf(a0[k]*w0.y + a1[k]*w1.y + xdx[k]*w2.y + xdy[k]*w3.y + he[k]*w4.y + w5.y, 0.f);
                hk[k].z = fmaxf(a0[k]*w0.z + a1[k]*w1.z + xdx[k]*w2.z + xdy[k]*w3.z + he[k]*w4.z + w5.z, 0.f);
                hk[k].w = fmaxf(a0[k]*w0.w + a1[k]*w1.w + xdx[k]*w2.w + xdy[k]*w3.w + he[k]*w4.w + w5.w, 0.f);
            }
        }
#pragma unroll
        for (int i = 0; i < 8; ++i) {
            float4 u = ((const float4*)sW[6 + i])[ci];
#pragma unroll
            for (int k = 0; k < 2; ++k)
                acc[k][i] += hk[k].x*u.x + hk[k].y*u.y + hk[k].z*u.z + hk[k].w*u.w;
        }
    }
#pragma unroll
    for (int k = 0; k < 2; ++k)
#pragma unroll
        for (int i = 0; i < 8; ++i) {
#pragma unroll
            for (int m = 1; m < 8; m <<= 1)
                acc[k][i] += __shfl_xor(acc[k][i], m);
        }
    if (g < 2) {
        int idx = i0 + g;
        int n = nbase + idx;
        if (idx < rem) {
            ((float2*)q2)[n]  = make_float2(acc[g][0] + bq2[0], acc[g][1] + bq2[1]);
            kv2[n] = make_float4(acc[g][2] + bk2[0], acc[g][3] + bk2[1],
                                 acc[g][4] + bv2[0], acc[g][5] + bv2[1]);
            ((float2*)hs2)[n] = make_float2(acc[g][6] + bs2[0], acc[g][7] + bs2[1]);
        }
    }
}

// Layer-2: one 128-dst bucket per block, 512 threads. int4 rec loads ->
// 4 concurrent kv2 gathers; LDS-atomic accumulate, in-block finalize +
// skip + closed-form 2-class log_softmax. (Verified rounds 20/21.)
__global__ __launch_bounds__(512) void l2out_k(
        const float* __restrict__ q2, const float4* __restrict__ kv2,
        const float* __restrict__ hs2,
        const int* __restrict__ recs, const int* __restrict__ cnt,
        float* __restrict__ out, int N) {
    __shared__ float qx[R_DSTS], qy[R_DSTS];
    __shared__ float ac[3 * R_DSTS];
    int t = threadIdx.x;
    int b = blockIdx.x;
    int nbase = b << R_LOG2;
    int rem = N - nbase; if (rem > R_DSTS) rem = R_DSTS;

    if (t < 3 * R_DSTS) ac[t] = 0.f;
    if (t < rem) {
        float2 q = ((const float2*)q2)[nbase + t];
        qx[t] = q.x * RSQRT2;
        qy[t] = q.y * RSQRT2;
    }
    __syncthreads();

    int cb = cnt[b]; if (cb > CAPB) cb = CAPB;
    const int* rb = recs + (size_t)b * CAPB;
    const int4* rb4 = (const int4*)rb;
    int nv4 = cb >> 2;
    for (int i = t; i < nv4; i += 512) {
        int4 r = rb4[i];
        int s0 = r.x & 0x1FFFF, d0 = (r.x >> 17) & (R_DSTS - 1);
        int s1 = r.y & 0x1FFFF, d1 = (r.y >> 17) & (R_DSTS - 1);
        int s2 = r.z & 0x1FFFF, d2 = (r.z >> 17) & (R_DSTS - 1);
        int s3 = r.w & 0x1FFFF, d3 = (r.w >> 17) & (R_DSTS - 1);
        float4 ka = kv2[s0];
        float4 kb = kv2[s1];
        float4 kc = kv2[s2];
        float4 kd = kv2[s3];
        float w0 = __expf(qx[d0] * ka.x + qy[d0] * ka.y);
        float w1 = __expf(qx[d1] * kb.x + qy[d1] * kb.y);
        float w2 = __expf(qx[d2] * kc.x + qy[d2] * kc.y);
        float w3 = __expf(qx[d3] * kd.x + qy[d3] * kd.y);
        atomicAdd(&ac[d0], w0); atomicAdd(&ac[R_DSTS + d0], w0 * ka.z); atomicAdd(&ac[2 * R_DSTS + d0], w0 * ka.w);
        atomicAdd(&ac[d1], w1); atomicAdd(&ac[R_DSTS + d1], w1 * kb.z); atomicAdd(&ac[2 * R_DSTS + d1], w1 * kb.w);
        atomicAdd(&ac[d2], w2); atomicAdd(&ac[R_DSTS + d2], w2 * kc.z); atomicAdd(&ac[2 * R_DSTS + d2], w2 * kc.w);
        atomicAdd(&ac[d3], w3); atomicAdd(&ac[R_DSTS + d3], w3 * kd.z); atomicAdd(&ac[2 * R_DSTS + d3], w3 * kd.w);
    }
    for (int i = (nv4 << 2) + t; i < cb; i += 512) {
        int rec = rb[i];
        int s = rec & 0x1FFFF;
        int dl = (rec >> 17) & (R_DSTS - 1);
        float4 kv = kv2[s];
        float w = __expf(qx[dl] * kv.x + qy[dl] * kv.y);
        atomicAdd(&ac[dl], w);
        atomicAdd(&ac[R_DSTS + dl], w * kv.z);
        atomicAdd(&ac[2 * R_DSTS + dl], w * kv.w);
    }
    __syncthreads();

    if (t < rem) {
        int n = nbase + t;
        float s = ac[t];
        float g0 = 0.f, g1 = 0.f;
        if (s > 0.f) {
            float inv = 1.0f / s;
            g0 = ac[R_DSTS + t] * inv; g1 = ac[2 * R_DSTS + t] * inv;
        }
        float2 hs = ((const float2*)hs2)[n];
        float o0 = g0 + hs.x;
        float o1 = g1 + hs.y;
        float mx = fmaxf(o0, o1), mn = fminf(o0, o1);
        float lse = mx + log1pf(__expf(mn - mx));
        ((float2*)out)[n] = make_float2(o0 - lse, o1 - lse);
    }
}

extern "C" void kernel_launch(void* const* d_in, const int* in_sizes, int n_in,
                              void* d_out, int out_size, void* d_ws, size_t ws_size,
                              hipStream_t stream) {
    const float* x   = (const float*)d_in[0];
    const int*   ei  = (const int*)d_in[1];
    const float* Wq1 = (const float*)d_in[2];
    const float* bq1 = (const float*)d_in[3];
    const float* Wk1 = (const float*)d_in[4];
    const float* bk1 = (const float*)d_in[5];
    const float* Wv1 = (const float*)d_in[6];
    const float* bv1 = (const float*)d_in[7];
    const float* Ws1 = (const float*)d_in[8];
    const float* bs1 = (const float*)d_in[9];
    const float* Wq2 = (const float*)d_in[10];
    const float* bq2 = (const float*)d_in[11];
    const float* Wk2 = (const float*)d_in[12];
    const float* bk2 = (const float*)d_in[13];
    const float* Wv2 = (const float*)d_in[14];
    const float* bv2 = (const float*)d_in[15];
    const float* Ws2 = (const float*)d_in[16];
    const float* bs2 = (const float*)d_in[17];

    const int N = in_sizes[0] / 2;
    const int E = in_sizes[1] / 2;
    const int* src = ei;
    const int* dst = ei + E;

    const int NB   = (N + R_DSTS - 1) >> R_LOG2;     // 782
    const int NBlk = (E + BE - 1) / BE;              // 391

    // workspace layout (4-byte units); recs at a 16B-aligned offset
    float* ws = (float*)d_ws;
    size_t off = 0;
    int*   cnt  = (int*)(ws + off);      off += MAXNB;             // padded
    int*   recs = (int*)(ws + off);      off += (size_t)NB * CAPB; // %4==0
    off = (off + 3) & ~(size_t)3;        // 16B align
    float4* kv2 = (float4*)(ws + off);   off += 4 * (size_t)N;
    float* q2   = ws + off;              off += 2 * (size_t)N;
    float* hs2  = ws + off;              off += 2 * (size_t)N;

    hipMemsetAsync(cnt, 0, NB * sizeof(int), stream);
    scatter1_k<<<NBlk, 1024, 0, stream>>>(src, dst, cnt, recs, NB, E);
    l1proj_k<<<NB, 512, 0, stream>>>(x, Wq1, bq1, Wk1, bk1,
                                     Wv1, bv1, Ws1, bs1,
                                     Wq2, bq2, Wk2, bk2, Wv2, bv2, Ws2, bs2,
                                     recs, cnt, q2, kv2, hs2, N);
    l2out_k<<<NB, 512, 0, stream>>>(q2, kv2, hs2, recs, cnt, (float*)d_out, N);
}

// Round 26
// 119.860 us; speedup vs baseline: 5.7392x; 1.0059x over previous
//
#include <hip/hip_runtime.h>

// ---------------------------------------------------------------------------
// 2-layer TransformerConv factored through the 2-dim feature spaces.
// Round 26: the agg/edge phases are unpipelined latency chains (1 int4
// iteration/thread) with only ~3 resident blocks/CU (grid-limited). Halve
// buckets (R_DSTS=64, NB=1564) and run the fused kernels at 256 threads ->
// ~6 independent block-chains per CU. Scatter reworked for 2048 bins.
// Pipeline: memset(cnt) -> scatter1 -> l1proj -> l2out (4 nodes).
// ---------------------------------------------------------------------------

#define R_LOG2   6
#define R_DSTS   64             // dsts per bucket
#define BE       4096           // edges per partition block
#define MAXNB    2048           // supports N <= 131072
#define CAPB     1216           // slots per bucket (mean 1024, ~6 sigma), %4==0
#define RSQRT2   0.70710678118654752f

// Single-pass locally-sorted scatter, 1024 threads (16 waves) per block.
// LDS histogram (2048 bins) -> in-block scan (2 entries/thread) -> global
// segment reservation -> rank & stage in bucket order -> ordered writes.
__global__ __launch_bounds__(1024) void scatter1_k(
        const int* __restrict__ src, const int* __restrict__ dst,
        int* __restrict__ cnt, int* __restrict__ recs, int NB, int E) {
    __shared__ int hist[MAXNB];
    __shared__ int lofs[MAXNB];
    __shared__ int gbase[MAXNB];
    __shared__ int stage[BE];
    __shared__ unsigned short sbkt[BE];
    __shared__ int wsum[16];
    int t = threadIdx.x;
    for (int i = t; i < NB; i += 1024) hist[i] = 0;
    __syncthreads();

    int base = blockIdx.x * BE;
    int nloc = E - base; if (nloc > BE) nloc = BE;
    int nv = nloc >> 2;
    const int4* d4 = (const int4*)(dst + base);
    const int4* s4 = (const int4*)(src + base);

    // pass 1: local histogram (4 edges/thread via int4)
    for (int i = t; i < nv; i += 1024) {
        int4 v = d4[i];
        atomicAdd(&hist[v.x >> R_LOG2], 1);
        atomicAdd(&hist[v.y >> R_LOG2], 1);
        atomicAdd(&hist[v.z >> R_LOG2], 1);
        atomicAdd(&hist[v.w >> R_LOG2], 1);
    }
    for (int i = (nv << 2) + t; i < nloc; i += 1024)
        atomicAdd(&hist[dst[base + i] >> R_LOG2], 1);
    __syncthreads();

    // in-block exclusive scan hist -> lofs (2 entries/thread, NB<=2048)
    {
        int i0 = 2 * t, i1 = 2 * t + 1;
        int a = (i0 < NB) ? hist[i0] : 0;
        int b = (i1 < NB) ? hist[i1] : 0;
        int s = a + b;
        int lane = t & 63, w = t >> 6;   // 16 waves
        int incl = s;
#pragma unroll
        for (int o = 1; o < 64; o <<= 1) {
            int u = __shfl_up(incl, o);
            if (lane >= o) incl += u;
        }
        if (lane == 63) wsum[w] = incl;
        __syncthreads();
        int ex = incl - s;
        for (int j = 0; j < w; ++j) ex += wsum[j];
        if (i0 < NB) lofs[i0] = ex;
        if (i1 < NB) lofs[i1] = ex + a;
    }
    __syncthreads();

    // reserve a contiguous segment in each touched bucket, reset hist
    for (int b = t; b < NB; b += 1024) {
        int h = hist[b];
        int start = h ? atomicAdd(&cnt[b], h) : 0;
        gbase[b] = b * CAPB + start - lofs[b];
        hist[b] = 0;
    }
    __syncthreads();

    // pass 2: rank & stage in bucket-sorted order
    for (int i = t; i < nv; i += 1024) {
        int4 dv = d4[i];
        int4 sv = s4[i];
        int d, b, r, p;
        d = dv.x; b = d >> R_LOG2; r = atomicAdd(&hist[b], 1); p = lofs[b] + r;
        stage[p] = sv.x | ((d & (R_DSTS - 1)) << 17); sbkt[p] = (unsigned short)b;
        d = dv.y; b = d >> R_LOG2; r = atomicAdd(&hist[b], 1); p = lofs[b] + r;
        stage[p] = sv.y | ((d & (R_DSTS - 1)) << 17); sbkt[p] = (unsigned short)b;
        d = dv.z; b = d >> R_LOG2; r = atomicAdd(&hist[b], 1); p = lofs[b] + r;
        stage[p] = sv.z | ((d & (R_DSTS - 1)) << 17); sbkt[p] = (unsigned short)b;
        d = dv.w; b = d >> R_LOG2; r = atomicAdd(&hist[b], 1); p = lofs[b] + r;
        stage[p] = sv.w | ((d & (R_DSTS - 1)) << 17); sbkt[p] = (unsigned short)b;
    }
    for (int i = (nv << 2) + t; i < nloc; i += 1024) {
        int d = dst[base + i];
        int b = d >> R_LOG2;
        int r = atomicAdd(&hist[b], 1);
        int p = lofs[b] + r;
        stage[p] = src[base + i] | ((d & (R_DSTS - 1)) << 17);
        sbkt[p] = (unsigned short)b;
    }
    __syncthreads();

    // pass 3: ordered write — consecutive i -> consecutive addresses per
    // segment; bound-checked against the bucket's fixed capacity.
    for (int i = t; i < nloc; i += 1024) {
        int bk = sbkt[i];
        int p = gbase[bk] + i;
        if (p < (bk + 1) * CAPB) recs[p] = stage[i];
    }
}

// Layer-1 bucket reduce FUSED with projection of the bucket's 64 nodes.
// One 64-dst bucket per block, 256 threads (1564 blocks, ~6/CU resident).
__global__ __launch_bounds__(256) void l1proj_k(
        const float* __restrict__ x,
        const float* __restrict__ Wq1, const float* __restrict__ bq1,
        const float* __restrict__ Wk1, const float* __restrict__ bk1,
        const float* __restrict__ Wv1, const float* __restrict__ bv1,
        const float* __restrict__ Ws1, const float* __restrict__ bs1,
        const float* __restrict__ Wq2, const float* __restrict__ bq2,
        const float* __restrict__ Wk2, const float* __restrict__ bk2,
        const float* __restrict__ Wv2, const float* __restrict__ bv2,
        const float* __restrict__ Ws2, const float* __restrict__ bs2,
        const int* __restrict__ recs, const int* __restrict__ cnt,
        float* __restrict__ q2, float4* __restrict__ kv2,
        float* __restrict__ hs2, int N) {
    __shared__ float cpart[4][9];
    __shared__ float c9[9];
    __shared__ float p0[R_DSTS], p1[R_DSTS], pc[R_DSTS];
    __shared__ float ac[3 * R_DSTS];
    __shared__ float sW[14][256];
    int t = threadIdx.x;

    // inline coeff reduction (alpha = xd^T M xs + u.xd + w.xs + c)
    {
        float wq0 = Wq1[t], wq1 = Wq1[256 + t];
        float wk0 = Wk1[t], wk1 = Wk1[256 + t];
        float bq = bq1[t], bk = bk1[t];
        float vals[9] = { wq0 * wk0, wq0 * wk1, wq1 * wk0, wq1 * wk1,
                          wq0 * bk,  wq1 * bk,  bq * wk0,  bq * wk1,  bq * bk };
        int lane = t & 63, w = t >> 6;
#pragma unroll
        for (int i = 0; i < 9; ++i) {
            float v = vals[i];
#pragma unroll
            for (int o = 32; o > 0; o >>= 1) v += __shfl_xor(v, o);
            if (lane == 0) cpart[w][i] = v;
        }
    }
    // weight staging (each thread loads its column of all 14 rows)
    sW[0][t]  = Wv1[t];
    sW[1][t]  = Wv1[256 + t];
    sW[2][t]  = Ws1[t];
    sW[3][t]  = Ws1[256 + t];
    sW[4][t]  = bv1[t];
    sW[5][t]  = bs1[t];
    sW[6][t]  = Wq2[2 * t];
    sW[7][t]  = Wq2[2 * t + 1];
    sW[8][t]  = Wk2[2 * t];
    sW[9][t]  = Wk2[2 * t + 1];
    sW[10][t] = Wv2[2 * t];
    sW[11][t] = Wv2[2 * t + 1];
    sW[12][t] = Ws2[2 * t];
    sW[13][t] = Ws2[2 * t + 1];
    __syncthreads();
    if (t < 9) c9[t] = cpart[0][t] + cpart[1][t] + cpart[2][t] + cpart[3][t];
    __syncthreads();

    int b = blockIdx.x;
    int nbase = b << R_LOG2;
    int rem = N - nbase; if (rem > R_DSTS) rem = R_DSTS;

    if (t < 3 * R_DSTS) ac[t] = 0.f;
    if (t < rem) {
        float2 xd = ((const float2*)x)[nbase + t];
        p0[t] = c9[0] * xd.x + c9[2] * xd.y + c9[6];
        p1[t] = c9[1] * xd.x + c9[3] * xd.y + c9[7];
        pc[t] = c9[4] * xd.x + c9[5] * xd.y + c9[8];
    }
    __syncthreads();

    // ---- bucket edge reduce (int4 rec loads, 4 concurrent gathers) ----
    const float2* x2 = (const float2*)x;
    int cb = cnt[b]; if (cb > CAPB) cb = CAPB;
    const int* rb = recs + (size_t)b * CAPB;
    const int4* rb4 = (const int4*)rb;
    int nv4 = cb >> 2;
    for (int i = t; i < nv4; i += 256) {
        int4 r = rb4[i];
        int s0 = r.x & 0x1FFFF, d0 = (r.x >> 17) & (R_DSTS - 1);
        int s1 = r.y & 0x1FFFF, d1 = (r.y >> 17) & (R_DSTS - 1);
        int s2 = r.z & 0x1FFFF, d2 = (r.z >> 17) & (R_DSTS - 1);
        int s3 = r.w & 0x1FFFF, d3 = (r.w >> 17) & (R_DSTS - 1);
        float2 xa = x2[s0];
        float2 xb = x2[s1];
        float2 xc = x2[s2];
        float2 xd = x2[s3];
        float w0 = __expf((p0[d0] * xa.x + p1[d0] * xa.y + pc[d0]) * 0.0625f);
        float w1 = __expf((p0[d1] * xb.x + p1[d1] * xb.y + pc[d1]) * 0.0625f);
        float w2 = __expf((p0[d2] * xc.x + p1[d2] * xc.y + pc[d2]) * 0.0625f);
        float w3 = __expf((p0[d3] * xd.x + p1[d3] * xd.y + pc[d3]) * 0.0625f);
        atomicAdd(&ac[d0], w0); atomicAdd(&ac[R_DSTS + d0], w0 * xa.x); atomicAdd(&ac[2 * R_DSTS + d0], w0 * xa.y);
        atomicAdd(&ac[d1], w1); atomicAdd(&ac[R_DSTS + d1], w1 * xb.x); atomicAdd(&ac[2 * R_DSTS + d1], w1 * xb.y);
        atomicAdd(&ac[d2], w2); atomicAdd(&ac[R_DSTS + d2], w2 * xc.x); atomicAdd(&ac[2 * R_DSTS + d2], w2 * xc.y);
        atomicAdd(&ac[d3], w3); atomicAdd(&ac[R_DSTS + d3], w3 * xd.x); atomicAdd(&ac[2 * R_DSTS + d3], w3 * xd.y);
    }
    for (int i = (nv4 << 2) + t; i < cb; i += 256) {
        int rec = rb[i];
        int s = rec & 0x1FFFF;
        int dl = (rec >> 17) & (R_DSTS - 1);
        float2 xs = x2[s];
        float w = __expf((p0[dl] * xs.x + p1[dl] * xs.y + pc[dl]) * 0.0625f);
        atomicAdd(&ac[dl], w);
        atomicAdd(&ac[R_DSTS + dl], w * xs.x);
        atomicAdd(&ac[2 * R_DSTS + dl], w * xs.y);
    }
    __syncthreads();

    // ---- fused projection of this bucket's 64 nodes ----
    // 8-lane group per TWO nodes: 256 threads = 32 groups x 2 = 64 nodes.
    int g = t & 7;
    int grp = t >> 3;                       // 0..31
    int i0 = grp * 2;                       // local node index base

    float a0[2], a1[2], he[2], xdx[2], xdy[2];
#pragma unroll
    for (int k = 0; k < 2; ++k) {
        int idx = i0 + k;
        int n = nbase + idx;
        a0[k] = 0.f; a1[k] = 0.f; he[k] = 0.f; xdx[k] = 0.f; xdy[k] = 0.f;
        if (idx < rem) {
            float s = ac[idx];              // LDS broadcast (full sums)
            if (s > 0.f) {
                float inv = 1.0f / s;
                a0[k] = ac[R_DSTS + idx] * inv;
                a1[k] = ac[2 * R_DSTS + idx] * inv;
                he[k] = 1.f;
            }
            float2 xd = ((const float2*)x)[n];
            xdx[k] = xd.x; xdy[k] = xd.y;
        }
    }

    float acc[2][8];
#pragma unroll
    for (int k = 0; k < 2; ++k)
#pragma unroll
        for (int i = 0; i < 8; ++i) acc[k][i] = 0.f;

#pragma unroll 1
    for (int j = 0; j < 8; ++j) {
        int ci = g + 8 * j;  // float4 index; channels 4*ci..4*ci+3
        float4 hk[2];
        {
            float4 w0 = ((const float4*)sW[0])[ci];
            float4 w1 = ((const float4*)sW[1])[ci];
            float4 w2 = ((const float4*)sW[2])[ci];
            float4 w3 = ((const float4*)sW[3])[ci];
            float4 w4 = ((const float4*)sW[4])[ci];
            float4 w5 = ((const float4*)sW[5])[ci];
#pragma unroll
            for (int k = 0; k < 2; ++k) {
                hk[k].x = fmaxf(a0[k]*w0.x + a1[k]*w1.x + xdx[k]*w2.x + xdy[k]*w3.x + he[k]*w4.x + w5.x, 0.f);
                hk[k].y = fmaxf(a0[k]*w0.y + a1[k]*w1.y + xdx[k]*w2.y + xdy[k]*w3.y + he[k]*w4.y + w5.y, 0.f);
                hk[k].z = fmaxf(a0[k]*w0.z + a1[k]*w1.z + xdx[k]*w2.z + xdy[k]*w3.z + he[k]*w4.z + w5.z, 0.f);
                hk[k].w = fmaxf(a0[k]*w0.w + a1[k]*w1.w + xdx[k]*w2.w + xdy[k]*w3.w + he[k]*w4.w + w5.w, 0.f);
            }
        }
#pragma unroll
        for (int i = 0; i < 8; ++i) {
            float4 u = ((const float4*)sW[6 + i])[ci];
#pragma unroll
            for (int k = 0; k < 2; ++k)
                acc[k][i] += hk[k].x*u.x + hk[k].y*u.y + hk[k].z*u.z + hk[k].w*u.w;
        }
    }
#pragma unroll
    for (int k = 0; k < 2; ++k)
#pragma unroll
        for (int i = 0; i < 8; ++i) {
#pragma unroll
            for (int m = 1; m < 8; m <<= 1)
                acc[k][i] += __shfl_xor(acc[k][i], m);
        }
    if (g < 2) {
        int idx = i0 + g;
        int n = nbase + idx;
        if (idx < rem) {
            ((float2*)q2)[n]  = make_float2(acc[g][0] + bq2[0], acc[g][1] + bq2[1]);
            kv2[n] = make_float4(acc[g][2] + bk2[0], acc[g][3] + bk2[1],
                                 acc[g][4] + bv2[0], acc[g][5] + bv2[1]);
            ((float2*)hs2)[n] = make_float2(acc[g][6] + bs2[0], acc[g][7] + bs2[1]);
        }
    }
}

// Layer-2: one 64-dst bucket per block, 256 threads. int4 rec loads ->
// 4 concurrent kv2 gathers; LDS-atomic accumulate, in-block finalize +
// skip + closed-form 2-class log_softmax.
__global__ __launch_bounds__(256) void l2out_k(
        const float* __restrict__ q2, const float4* __restrict__ kv2,
        const float* __restrict__ hs2,
        const int* __restrict__ recs, const int* __restrict__ cnt,
        float* __restrict__ out, int N) {
    __shared__ float qx[R_DSTS], qy[R_DSTS];
    __shared__ float ac[3 * R_DSTS];
    int t = threadIdx.x;
    int b = blockIdx.x;
    int nbase = b << R_LOG2;
    int rem = N - nbase; if (rem > R_DSTS) rem = R_DSTS;

    if (t < 3 * R_DSTS) ac[t] = 0.f;
    if (t < rem) {
        float2 q = ((const float2*)q2)[nbase + t];
        qx[t] = q.x * RSQRT2;
        qy[t] = q.y * RSQRT2;
    }
    __syncthreads();

    int cb = cnt[b]; if (cb > CAPB) cb = CAPB;
    const int* rb = recs + (size_t)b * CAPB;
    const int4* rb4 = (const int4*)rb;
    int nv4 = cb >> 2;
    for (int i = t; i < nv4; i += 256) {
        int4 r = rb4[i];
        int s0 = r.x & 0x1FFFF, d0 = (r.x >> 17) & (R_DSTS - 1);
        int s1 = r.y & 0x1FFFF, d1 = (r.y >> 17) & (R_DSTS - 1);
        int s2 = r.z & 0x1FFFF, d2 = (r.z >> 17) & (R_DSTS - 1);
        int s3 = r.w & 0x1FFFF, d3 = (r.w >> 17) & (R_DSTS - 1);
        float4 ka = kv2[s0];
        float4 kb = kv2[s1];
        float4 kc = kv2[s2];
        float4 kd = kv2[s3];
        float w0 = __expf(qx[d0] * ka.x + qy[d0] * ka.y);
        float w1 = __expf(qx[d1] * kb.x + qy[d1] * kb.y);
        float w2 = __expf(qx[d2] * kc.x + qy[d2] * kc.y);
        float w3 = __expf(qx[d3] * kd.x + qy[d3] * kd.y);
        atomicAdd(&ac[d0], w0); atomicAdd(&ac[R_DSTS + d0], w0 * ka.z); atomicAdd(&ac[2 * R_DSTS + d0], w0 * ka.w);
        atomicAdd(&ac[d1], w1); atomicAdd(&ac[R_DSTS + d1], w1 * kb.z); atomicAdd(&ac[2 * R_DSTS + d1], w1 * kb.w);
        atomicAdd(&ac[d2], w2); atomicAdd(&ac[R_DSTS + d2], w2 * kc.z); atomicAdd(&ac[2 * R_DSTS + d2], w2 * kc.w);
        atomicAdd(&ac[d3], w3); atomicAdd(&ac[R_DSTS + d3], w3 * kd.z); atomicAdd(&ac[2 * R_DSTS + d3], w3 * kd.w);
    }
    for (int i = (nv4 << 2) + t; i < cb; i += 256) {
        int rec = rb[i];
        int s = rec & 0x1FFFF;
        int dl = (rec >> 17) & (R_DSTS - 1);
        float4 kv = kv2[s];
        float w = __expf(qx[dl] * kv.x + qy[dl] * kv.y);
        atomicAdd(&ac[dl], w);
        atomicAdd(&ac[R_DSTS + dl], w * kv.z);
        atomicAdd(&ac[2 * R_DSTS + dl], w * kv.w);
    }
    __syncthreads();

    if (t < rem) {
        int n = nbase + t;
        float s = ac[t];
        float g0 = 0.f, g1 = 0.f;
        if (s > 0.f) {
            float inv = 1.0f / s;
            g0 = ac[R_DSTS + t] * inv; g1 = ac[2 * R_DSTS + t] * inv;
        }
        float2 hs = ((const float2*)hs2)[n];
        float o0 = g0 + hs.x;
        float o1 = g1 + hs.y;
        float mx = fmaxf(o0, o1), mn = fminf(o0, o1);
        float lse = mx + log1pf(__expf(mn - mx));
        ((float2*)out)[n] = make_float2(o0 - lse, o1 - lse);
    }
}

extern "C" void kernel_launch(void* const* d_in, const int* in_sizes, int n_in,
                              void* d_out, int out_size, void* d_ws, size_t ws_size,
                              hipStream_t stream) {
    const float* x   = (const float*)d_in[0];
    const int*   ei  = (const int*)d_in[1];
    const float* Wq1 = (const float*)d_in[2];
    const float* bq1 = (const float*)d_in[3];
    const float* Wk1 = (const float*)d_in[4];
    const float* bk1 = (const float*)d_in[5];
    const float* Wv1 = (const float*)d_in[6];
    const float* bv1 = (const float*)d_in[7];
    const float* Ws1 = (const float*)d_in[8];
    const float* bs1 = (const float*)d_in[9];
    const float* Wq2 = (const float*)d_in[10];
    const float* bq2 = (const float*)d_in[11];
    const float* Wk2 = (const float*)d_in[12];
    const float* bk2 = (const float*)d_in[13];
    const float* Wv2 = (const float*)d_in[14];
    const float* bv2 = (const float*)d_in[15];
    const float* Ws2 = (const float*)d_in[16];
    const float* bs2 = (const float*)d_in[17];

    const int N = in_sizes[0] / 2;
    const int E = in_sizes[1] / 2;
    const int* src = ei;
    const int* dst = ei + E;

    const int NB   = (N + R_DSTS - 1) >> R_LOG2;     // 1563
    const int NBlk = (E + BE - 1) / BE;              // 391

    // workspace layout (4-byte units); recs at a 16B-aligned offset
    float* ws = (float*)d_ws;
    size_t off = 0;
    int*   cnt  = (int*)(ws + off);      off += MAXNB;             // padded
    int*   recs = (int*)(ws + off);      off += (size_t)NB * CAPB; // %4==0
    off = (off + 3) & ~(size_t)3;        // 16B align
    float4* kv2 = (float4*)(ws + off);   off += 4 * (size_t)N;
    float* q2   = ws + off;              off += 2 * (size_t)N;
    float* hs2  = ws + off;              off += 2 * (size_t)N;

    hipMemsetAsync(cnt, 0, NB * sizeof(int), stream);
    scatter1_k<<<NBlk, 1024, 0, stream>>>(src, dst, cnt, recs, NB, E);
    l1proj_k<<<NB, 256, 0, stream>>>(x, Wq1, bq1, Wk1, bk1,
                                     Wv1, bv1, Ws1, bs1,
                                     Wq2, bq2, Wk2, bk2, Wv2, bv2, Ws2, bs2,
                                     recs, cnt, q2, kv2, hs2, N);
    l2out_k<<<NB, 256, 0, stream>>>(q2, kv2, hs2, recs, cnt, (float*)d_out, N);
}